// Round 6
// baseline (302.080 us; speedup 1.0000x reference)
//
#include <hip/hip_runtime.h>

// FFT long conv: out[b,d,l] = (1/16384^2 forward-norm pair) * linear conv of x,f, masked.
// One workgroup per (b,d) channel; 3 complex FFTs (2 fwd + 1 packed inverse) in 128KB LDS.
//
// R7: cut LDS round-trips 14 -> 8 (traffic 1.79 -> 1.15 MB/block).
//  * First fwd pass (stages 12..10) computed IN REGISTERS from the global load (its
//    element set t + k*1024 is exactly the coalesced load pattern). B-branch reloads
//    x,f immediately (64KB, L2-hot) so live regs stay ~24 (spill rule from R5).
//  * 5-stage merged LDS passes: ownership maps put 2 butterfly bits in LANE bits
//    (t1,t0) -> 3 stages in-register + 2 stages via mov_dpp quad-perm (xor2/xor1,
//    pure VALU). Twiddles all derive from one sincos per pass: T8=T4^2, T16=T8^2 with
//    sign factors (-1)^{t1}/(-1)^{t0} (upper lane's own T^8/T^16 equals -W_true).
//    FFT schedule: regs{12-10} -> LDS{9-5} -> LDS{4-0}; inverse mirrored ascending.
//  * New swizzle SWZ(i) = i ^ (((i>>5)&15)<<1) matched to the new pass maps: every
//    pass's read/write set lands exactly 4 accesses/bank-pair (b64 floor).
//  * Pack + 3-FFT algorithm unchanged from R6 (verified, absmax 1.2e-4).
//
// positions arrives as int32 from the harness (int64 in the npz) - keep const int*.

#define N_FFT 8192
#define NT    1024
#define PI_F  3.14159265358979323846f
#define RS2   0.70710678118654752440f

__device__ __forceinline__ float2 cmul(float2 a, float2 b) {
    return make_float2(a.x * b.x - a.y * b.y, a.x * b.y + a.y * b.x);
}
__device__ __forceinline__ float2 cadd(float2 a, float2 b) { return make_float2(a.x + b.x, a.y + b.y); }
__device__ __forceinline__ float2 csub(float2 a, float2 b) { return make_float2(a.x - b.x, a.y - b.y); }
__device__ __forceinline__ float2 mneg_i(float2 a) { return make_float2(a.y, -a.x); }  // a * (-i)
__device__ __forceinline__ float2 mpos_i(float2 a) { return make_float2(-a.y, a.x); }  // a * (+i)

__device__ __forceinline__ int rev13(int v) { return (int)(__brev((unsigned)v) >> 19); }
// LDS swizzle (float2 units): XOR bits 4..1 with bits 8..5. Involution, bijective.
__device__ __forceinline__ int SWZ(int i) { return i ^ (((i >> 5) & 15) << 1); }

// quad-perm DPP lane exchange: xor1 = {1,0,3,2} = 0xB1, xor2 = {2,3,0,1} = 0x4E
__device__ __forceinline__ float dppx1(float v) {
    return __int_as_float(__builtin_amdgcn_mov_dpp(__float_as_int(v), 0xB1, 0xF, 0xF, true));
}
__device__ __forceinline__ float dppx2(float v) {
    return __int_as_float(__builtin_amdgcn_mov_dpp(__float_as_int(v), 0x4E, 0xF, 0xF, true));
}
__device__ __forceinline__ float2 dppx1v(float2 v) { return make_float2(dppx1(v.x), dppx1(v.y)); }
__device__ __forceinline__ float2 dppx2v(float2 v) { return make_float2(dppx2(v.x), dppx2(v.y)); }

// ---- forward DIF core: 3 stages on r[8] (pairs k^4, k^2, k^1), base twiddle
//      T1 = e^{-i pi lo / 2^(b+2)} where lo = element low bits below the k-field.
//      SH: append 2 more DIF stages whose partner bits are lane bits t1,t0
//      (element bits b-1,b-2). Upper lane's own T8/T16 = -W_true (derived &
//      verified at stages {6,5} and {1,0}); lower lanes don't apply a twiddle. ----
template <bool SH>
__device__ __forceinline__ void fwd_core(float2 r[8], float2 T1, int t) {
    const float2 T2  = cmul(T1, T1);
    const float2 T4  = cmul(T2, T2);
    const float2 T1b = cmul(T1, make_float2(RS2, -RS2));       // T1 * e^{-i pi/4}
#pragma unroll
    for (int k = 0; k < 4; ++k) {                               // stage b+2
        float2 u = r[k], v = r[k + 4];
        r[k] = cadd(u, v);
        float2 d  = csub(u, v);
        float2 tw = (k == 0) ? T1 : (k == 1) ? T1b : (k == 2) ? mneg_i(T1) : mneg_i(T1b);
        r[k + 4] = cmul(d, tw);
    }
#pragma unroll
    for (int k0 = 0; k0 < 8; k0 += 4) {                         // stage b+1
#pragma unroll
        for (int kk = 0; kk < 2; ++kk) {
            const int k = k0 + kk;
            float2 u = r[k], v = r[k + 2];
            r[k] = cadd(u, v);
            r[k + 2] = cmul(csub(u, v), kk ? mneg_i(T2) : T2);
        }
    }
#pragma unroll
    for (int k = 0; k < 8; k += 2) {                            // stage b
        float2 u = r[k], v = r[k + 1];
        r[k] = cadd(u, v);
        r[k + 1] = cmul(csub(u, v), T4);
    }
    if constexpr (SH) {
        const float2 T8  = cmul(T4, T4);
        const float2 T16 = cmul(T8, T8);
        const float2 W2  = make_float2(-T8.x,  -T8.y);          // dist-2 stage, upper lanes
        const float2 W1  = make_float2(-T16.x, -T16.y);         // dist-1 stage, upper lanes
        const bool u2 = (t & 2) != 0, u1 = (t & 1) != 0;
#pragma unroll
        for (int k = 0; k < 8; ++k) {                           // stage b-1 (lane bit t1)
            float2 o = dppx2v(r[k]);
            float2 s = u2 ? csub(o, r[k]) : cadd(r[k], o);
            r[k] = u2 ? cmul(s, W2) : s;
        }
#pragma unroll
        for (int k = 0; k < 8; ++k) {                           // stage b-2 (lane bit t0)
            float2 o = dppx1v(r[k]);
            float2 s = u1 ? csub(o, r[k]) : cadd(r[k], o);
            r[k] = u1 ? cmul(s, W1) : s;
        }
    }
}

// ---- inverse DIT core: SH prepends the two lane-bit stages (ascending: t0 then t1);
//      for both, each lane's update is r = (up ? o : r) + U^{16|8}_own * (up ? r : o),
//      which equals the true butterfly because upper's own U^n = -W_true. ----
template <bool SH>
__device__ __forceinline__ void inv_core(float2 r[8], float2 U1, int t) {
    const float2 U2 = cmul(U1, U1);
    const float2 U4 = cmul(U2, U2);
    if constexpr (SH) {
        const float2 U8  = cmul(U4, U4);
        const float2 U16 = cmul(U8, U8);
        const bool u1 = (t & 1) != 0, u2 = (t & 2) != 0;
#pragma unroll
        for (int k = 0; k < 8; ++k) {                           // stage b-2 (lane bit t0)
            float2 o = dppx1v(r[k]);
            float2 m = cmul(U16, u1 ? r[k] : o);
            r[k] = cadd(u1 ? o : r[k], m);
        }
#pragma unroll
        for (int k = 0; k < 8; ++k) {                           // stage b-1 (lane bit t1)
            float2 o = dppx2v(r[k]);
            float2 m = cmul(U8, u2 ? r[k] : o);
            r[k] = cadd(u2 ? o : r[k], m);
        }
    }
    const float2 U1b = cmul(U1, make_float2(RS2, RS2));         // U1 * e^{+i pi/4}
#pragma unroll
    for (int k = 0; k < 8; k += 2) {                            // stage b
        float2 u = r[k];
        float2 v = cmul(r[k + 1], U4);
        r[k] = cadd(u, v);
        r[k + 1] = csub(u, v);
    }
#pragma unroll
    for (int k0 = 0; k0 < 8; k0 += 4) {                         // stage b+1
#pragma unroll
        for (int kk = 0; kk < 2; ++kk) {
            const int k = k0 + kk;
            float2 u = r[k];
            float2 v = cmul(r[k + 2], kk ? mpos_i(U2) : U2);
            r[k] = cadd(u, v);
            r[k + 2] = csub(u, v);
        }
    }
#pragma unroll
    for (int k = 0; k < 4; ++k) {                               // stage b+2
        float2 tw = (k == 0) ? U1 : (k == 1) ? U1b : (k == 2) ? mpos_i(U1) : mpos_i(U1b);
        float2 u = r[k];
        float2 v = cmul(r[k + 4], tw);
        r[k] = cadd(u, v);
        r[k + 4] = csub(u, v);
    }
}

// Z1 = W_k, Z2 = W_{16384-k} of combined x+i*f spectrum -> Yhat_k = Xhat_k*Fhat_k*scale.
__device__ __forceinline__ float2 pw(float2 z1, float2 z2, float scale) {
    float2 X = make_float2(0.5f * (z1.x + z2.x), 0.5f * (z1.y - z2.y));
    float2 D = make_float2(z1.x - z2.x, z1.y + z2.y);
    float2 F = make_float2(0.5f * D.y, -0.5f * D.x);
    float2 Y = cmul(X, F);
    return make_float2(Y.x * scale, Y.y * scale);
}

// irfft pack: G = (P + conj Q) + i*E*(P - conj Q)
__device__ __forceinline__ float2 gpack(float2 P, float2 Q, float2 E) {
    float2 S  = make_float2(P.x + Q.x, P.y - Q.y);
    float2 Dd = make_float2(P.x - Q.x, P.y + Q.y);
    float2 iE = make_float2(-E.y, E.x);
    return cadd(S, cmul(iE, Dd));
}

__global__ void __launch_bounds__(NT)
fftconv_kernel(const float* __restrict__ x, const float* __restrict__ f,
               const int* __restrict__ pos, float* __restrict__ out) {
    __shared__ float2 A[N_FFT];                 // We spectrum / G / inverse workspace
    __shared__ float2 Bb[N_FFT];                // Wo spectrum
    const int t   = threadIdx.x;
    const int cch = blockIdx.x;                 // channel b*256 + d
    const int bb  = cch >> 8;
    const size_t gbase = (size_t)cch * N_FFT;

    const float scale = 1.0f / (16384.0f * 16384.0f);  // two forward-norm 1/n factors
    float2 r[8];
    float sn, cs;

    // --- pass address bases (all SWZ-folded; k-terms XOR-combine, no carries) ---
    // regs/I3 pass (bits 12..10): e = (k<<10)|t            -> addr = sbR + (k<<10)
    const int sbR = t ^ (((t >> 5) & 15) << 1);
    // P2/I2 pass (bits 9..5): e = (t[9:7]<<10)|(k<<7)|(t[1:0]<<5)|t[6:2]
    //   SWZ mask = ((k&3)<<2 | t[1:0])<<1                  -> addr = sb2 ^ kk2[k]
    const int sb2 = ((((t >> 7) << 10) | ((t & 3) << 5) | ((t >> 2) & 31))) ^ ((t & 3) << 1);
    const int kk2[8] = {0, 136, 272, 408, 512, 648, 784, 920};   // (k<<7)|((k&3)<<3)
    // P3/I1 pass (bits 4..0): e = (t[9:2]<<5)|(k<<2)|t[1:0]
    //   SWZ mask = t[5:2]<<1 (k-independent)               -> addr = sb3 ^ (k<<2)
    const int sb3 = ((((t >> 2) << 5) | (t & 3))) ^ (((t >> 2) & 15) << 1);

    // cos/sin(pi*k/8) for the odd-branch modulation (m = k*1024 + t)
    const float C8[8] = {1.0f, 0.92387953f, 0.70710678f, 0.38268343f,
                         0.0f, -0.38268343f, -0.70710678f, -0.92387953f};
    const float S8[8] = {0.0f, 0.38268343f, 0.70710678f, 0.92387953f,
                         1.0f, 0.92387953f, 0.70710678f, 0.38268343f};
    const float lowf = (float)(((t & 3) << 5) | ((t >> 2) & 31));  // P2/I2 twiddle index

    // ==== seg 1: load + first fwd pass (stages 12..10) in REGISTERS ====
    __sincosf(-PI_F * (float)t / 4096.0f, &sn, &cs);
    const float2 T1R = make_float2(cs, sn);
    // A branch: w = x + i f
#pragma unroll
    for (int k = 0; k < 8; ++k) {
        const int m = k * NT + t;
        r[k] = make_float2(x[gbase + m], f[gbase + m]);
    }
    fwd_core<false>(r, T1R, t);
#pragma unroll
    for (int k = 0; k < 8; ++k) A[sbR + (k << 10)] = r[k];
    // B branch: reload (L2-hot, keeps live regs low per R5 spill rule), modulate
    __sincosf(-PI_F * (float)t / 8192.0f, &sn, &cs);
    const float2 Bt = make_float2(cs, sn);
#pragma unroll
    for (int k = 0; k < 8; ++k) {
        const int m = k * NT + t;
        const float2 wq = make_float2(x[gbase + m], f[gbase + m]);
        const float2 tw = cmul(Bt, make_float2(C8[k], -S8[k]));  // e^{-i pi m/8192}
        r[k] = cmul(wq, tw);
    }
    fwd_core<false>(r, T1R, t);
#pragma unroll
    for (int k = 0; k < 8; ++k) Bb[sbR + (k << 10)] = r[k];
    __syncthreads();

    // ==== P2: fwd stages 9..5 (3 in-reg + 2 DPP) on A then B ====
    __sincosf(-PI_F * lowf / 512.0f, &sn, &cs);
    const float2 L1 = make_float2(cs, sn);
#pragma unroll
    for (int k = 0; k < 8; ++k) r[k] = A[sb2 ^ kk2[k]];
    fwd_core<true>(r, L1, t);
#pragma unroll
    for (int k = 0; k < 8; ++k) A[sb2 ^ kk2[k]] = r[k];
#pragma unroll
    for (int k = 0; k < 8; ++k) r[k] = Bb[sb2 ^ kk2[k]];
    fwd_core<true>(r, L1, t);
#pragma unroll
    for (int k = 0; k < 8; ++k) Bb[sb2 ^ kk2[k]] = r[k];
    __syncthreads();

    // ==== P3: fwd stages 4..0 on A then B -> full DIF spectra, bit-reversed ====
    __sincosf(-PI_F * (float)(t & 3) / 16.0f, &sn, &cs);
    const float2 M1 = make_float2(cs, sn);
#pragma unroll
    for (int k = 0; k < 8; ++k) r[k] = A[sb3 ^ (k << 2)];
    fwd_core<true>(r, M1, t);
#pragma unroll
    for (int k = 0; k < 8; ++k) A[sb3 ^ (k << 2)] = r[k];
#pragma unroll
    for (int k = 0; k < 8; ++k) r[k] = Bb[sb3 ^ (k << 2)];
    fwd_core<true>(r, M1, t);
#pragma unroll
    for (int k = 0; k < 8; ++k) Bb[sb3 ^ (k << 2)] = r[k];
    __syncthreads();

    // ==== pointwise + irfft pack: build Ghat (bitrev) into A (verified in R6) ====
    {
        float2 Gv[8];
        int    Ga[8];
        const float DC = 0.99999992646f;        // cos(pi/8192)
        const float DS = 3.83495188e-4f;        // sin(pi/8192)
#pragma unroll
        for (int q = 0; q < 2; ++q) {
            const int j = (q << 10) | ((t & 7) << 7) | (t >> 3);   // bijective [0,2048)
            const int b = rev13(j);
            float sn2, cs2;
            __sincosf(PI_F * (float)j / 4096.0f, &sn2, &cs2);
            const float2 E  = make_float2(cs2, sn2);               // e^{i pi 2j/8192}
            const float2 Eo = cmul(E, make_float2(DC, DS));        // e^{i pi (2j+1)/8192}

            if (j == 0) {
                // specials: G_0 (from Ye[0], Ye[4096]) and G_4096 (= 2 conj(Ye[2048]))
                float2 a0 = A[SWZ(0)], a1 = A[SWZ(1)], a2 = A[SWZ(2)], a3 = A[SWZ(3)];
                float2 P0 = pw(a0, a0, scale);     // Ye[0]
                float2 Q0 = pw(a1, a1, scale);     // Ye[4096]
                float2 P2 = pw(a2, a3, scale);     // Ye[2048]
                Gv[0] = gpack(P0, Q0, make_float2(1.0f, 0.0f)); Ga[0] = 0;   // rev13(0)
                Gv[1] = make_float2(2.0f * P2.x, -2.0f * P2.y); Ga[1] = 1;   // rev13(4096)
            } else {
                const int c = rev13(4096 - j);
                float2 z1 = A[SWZ(b)];       // We[j]
                float2 z2 = A[SWZ(c + 1)];   // We[8192-j]
                float2 z3 = A[SWZ(c)];       // We[4096-j]
                float2 z4 = A[SWZ(b + 1)];   // We[4096+j]
                float2 P = pw(z1, z2, scale);                    // Yprod_{2j}
                float2 Q = pw(z3, z4, scale);                    // Yprod_{8192-2j}
                Gv[q * 4 + 0] = gpack(P, Q, E);                       Ga[q * 4 + 0] = b >> 1;
                Gv[q * 4 + 1] = gpack(Q, P, make_float2(-E.x, E.y));  Ga[q * 4 + 1] = c >> 1;
            }
            {   // odd bins 2j+1 and 8191-2j (no specials)
                const int na = 8191 - b;      // rev13(8191-j)
                float2 z1 = Bb[SWZ(b)];       // Wo[j]
                float2 z2 = Bb[SWZ(na)];      // Wo[8191-j]
                float2 z3 = Bb[SWZ(na - 1)];  // Wo[4095-j]
                float2 z4 = Bb[SWZ(b + 1)];   // Wo[4096+j]
                float2 P = pw(z1, z2, scale);                    // Yprod_{2j+1}
                float2 Q = pw(z3, z4, scale);                    // Yprod_{8191-2j}
                Gv[q * 4 + 2] = gpack(P, Q, Eo);                        Ga[q * 4 + 2] = (b >> 1) | 4096;
                Gv[q * 4 + 3] = gpack(Q, P, make_float2(-Eo.x, Eo.y));  Ga[q * 4 + 3] = 8191 - (b >> 1);
            }
        }
        __syncthreads();   // all We/Wo reads complete before overwriting A with G
#pragma unroll
        for (int u = 0; u < 8; ++u) A[SWZ(Ga[u])] = Gv[u];
    }
    __syncthreads();

    // ==== inverse: c = IDFT_8192(Ghat), c_j = y_{2j} + i y_{2j+1} ====
    // I1: stages 0..4 (2 DPP + 3 in-reg)
    __sincosf(PI_F * (float)(t & 3) / 16.0f, &sn, &cs);
    const float2 Mi = make_float2(cs, sn);
#pragma unroll
    for (int k = 0; k < 8; ++k) r[k] = A[sb3 ^ (k << 2)];
    inv_core<true>(r, Mi, t);
#pragma unroll
    for (int k = 0; k < 8; ++k) A[sb3 ^ (k << 2)] = r[k];
    __syncthreads();

    // I2: stages 5..9
    __sincosf(PI_F * lowf / 512.0f, &sn, &cs);
    const float2 Li = make_float2(cs, sn);
#pragma unroll
    for (int k = 0; k < 8; ++k) r[k] = A[sb2 ^ kk2[k]];
    inv_core<true>(r, Li, t);
#pragma unroll
    for (int k = 0; k < 8; ++k) A[sb2 ^ kk2[k]] = r[k];
    __syncthreads();

    // I3: stages 10..12, result stays in registers (r[k] = c at index k*1024 + t)
    __sincosf(PI_F * (float)t / 4096.0f, &sn, &cs);
    const float2 Vi = make_float2(cs, sn);
#pragma unroll
    for (int k = 0; k < 8; ++k) r[k] = A[sbR + (k << 10)];
    inv_core<false>(r, Vi, t);

    // ==== store first half (j < 4096 <=> m < 8192), masked, coalesced float2 ====
    {
        float2* out2 = (float2*)out + (size_t)cch * 4096;
        const int2* pos2 = (const int2*)(pos) + (size_t)bb * 4096;
#pragma unroll
        for (int k = 0; k < 4; ++k) {
            const int j = k * NT + t;
            const int2 pp = pos2[j];
            const float2 v = r[k];
            out2[j] = make_float2(pp.x != -1 ? v.x : 0.0f,
                                  pp.y != -1 ? v.y : 0.0f);
        }
    }
}

extern "C" void kernel_launch(void* const* d_in, const int* in_sizes, int n_in,
                              void* d_out, int out_size, void* d_ws, size_t ws_size,
                              hipStream_t stream) {
    const float* x   = (const float*)d_in[0];
    const float* f   = (const float*)d_in[1];
    const int*   pos = (const int*)d_in[2];
    float*       out = (float*)d_out;
    (void)in_sizes; (void)n_in; (void)out_size; (void)d_ws; (void)ws_size;

    // B*D = 8*256 = 2048 channels, one block each
    fftconv_kernel<<<2048, NT, 0, stream>>>(x, f, pos, out);
}